// Round 21
// baseline (118.076 us; speedup 1.0000x reference)
//
#include <hip/hip_runtime.h>
#include <stdint.h>

// Problem constants: B=2, N=2048, D=1024, HEADS=16, DH=64, SCALE=0.125
using bf16x8 = __attribute__((ext_vector_type(8))) short;
using f32x4  = __attribute__((ext_vector_type(4))) float;
using s16x4  = __attribute__((ext_vector_type(4))) short;

__device__ __forceinline__ short f2bf(float f) {
    union { float f; uint32_t u; } v; v.f = f;
    uint32_t u = v.u;
    uint32_t r = (u + 0x7fffu + ((u >> 16) & 1u)) >> 16;  // RNE
    return (short)r;
}

__device__ __forceinline__ uint32_t cvtpk_bf16(float a, float b) {
    uint32_t r;
    asm("v_cvt_pk_bf16_f32 %0, %1, %2" : "=v"(r) : "v"(a), "v"(b));
    return r;  // lo = bf16(a), hi = bf16(b)
}

// async global->LDS, 16B per lane; LDS dest = wave-uniform base + lane*16
__device__ __forceinline__ void gload_lds16(const void* g, void* l) {
    __builtin_amdgcn_global_load_lds(
        reinterpret_cast<const uint32_t __attribute__((address_space(1)))*>(
            reinterpret_cast<uintptr_t>(g)),
        reinterpret_cast<uint32_t __attribute__((address_space(3)))*>(
            reinterpret_cast<uintptr_t>(l)),
        16, 0, 0);
}

// ---------------- fused fp32 -> bf16 conversion (x + 4 weights) -------------
__global__ __launch_bounds__(256) void cvt_all(
    const float* __restrict__ x, const float* __restrict__ wq,
    const float* __restrict__ wk, const float* __restrict__ wv,
    const float* __restrict__ wo,
    short* __restrict__ xb, short* __restrict__ wqb, short* __restrict__ wkb,
    short* __restrict__ wvb, short* __restrict__ wob)
{
    int i = blockIdx.x * 256 + threadIdx.x;   // float4 index, total 2097152
    const float* src; short* dst; int off;
    if      (i < 1048576) { src = x;  dst = xb;  off = i; }
    else if (i < 1310720) { src = wq; dst = wqb; off = i - 1048576; }
    else if (i < 1572864) { src = wk; dst = wkb; off = i - 1310720; }
    else if (i < 1835008) { src = wv; dst = wvb; off = i - 1572864; }
    else                  { src = wo; dst = wob; off = i - 1835008; }
    float4 f = ((const float4*)src)[off];
    s16x4 r; r[0] = f2bf(f.x); r[1] = f2bf(f.y); r[2] = f2bf(f.z); r[3] = f2bf(f.w);
    ((s16x4*)dst)[off] = r;
}

// ---------------- GEMM: C = A(MxK) * B(NxK)^T, bf16, 128x64 tile ------------
// Grid 1536 (QKV) / 512 (out), 48KB LDS, 3 blocks/CU. XCD-bijective swizzle.
// NEW (R21): single-barrier K-loop (R17-verified pattern) -- iteration =
// {vmcnt(0); barrier; GSTAGE(kt+1); compute(kt)}. At the barrier every
// wave's compute(kt-1) ds_reads completed (MFMA operand dependency + program
// order), so GSTAGE(kt+1) writing buf[(kt+1)&1] cannot race them; stager's
// vmcnt(0) before the barrier publishes buf[kt&1]. Removes 16 barriers +
// 16 lgkmcnt(0) drains per block. V^T (z==2) written KV-PI-PERMUTED (R16).
template <bool IS_OUT>
__global__ __launch_bounds__(256) void gemm_bt(
    const short* __restrict__ A,
    const short* __restrict__ Bq, const short* __restrict__ Bk,
    const short* __restrict__ Bv,
    short* __restrict__ qb, short* __restrict__ kb, short* __restrict__ vtb,
    float* __restrict__ outp, const float* __restrict__ bias)
{
    __shared__ short As[2][128 * 64];
    __shared__ short Bs[2][64 * 64];
    const int tid  = threadIdx.x;
    const int wave = tid >> 6, lane = tid & 63;
    const int lo = lane & 15, hi = lane >> 4;

    // swizzle: linear id -> XCD-contiguous chunk, then decomposition
    const int nwg = gridDim.x * gridDim.y * gridDim.z;
    int lin = blockIdx.x + blockIdx.y * gridDim.x +
              blockIdx.z * gridDim.x * gridDim.y;
    const int s = (lin & 7) * (nwg >> 3) + (lin >> 3);
    const int m_base = ((s >> 4) & 31) * 128;
    const int n_base = (s & 15) * 64;
    const int z = IS_OUT ? 0 : (s >> 9);

    const short* Bw = IS_OUT ? Bq : (z == 0 ? Bq : (z == 1 ? Bk : Bv));
    const int wr = wave >> 1, wc = wave & 1;

    f32x4 acc[4][2];
#pragma unroll
    for (int i = 0; i < 4; ++i)
#pragma unroll
        for (int j = 0; j < 2; ++j) acc[i][j] = (f32x4){0.f, 0.f, 0.f, 0.f};

    const int se = (lane & 7) * 8;
    const short* Ag = A  + (size_t)(m_base + wave * 32 + (lane >> 3)) * 1024 + se;
    const short* Bg = Bw + (size_t)(n_base + wave * 16 + (lane >> 3)) * 1024 + se;

    auto GSTAGE = [&](int kt) {
        const int k0 = kt * 64, bf = kt & 1;
#pragma unroll
        for (int c = 0; c < 4; ++c)
            gload_lds16(Ag + (size_t)c * 8 * 1024 + k0, &As[bf][(wave * 32 + c * 8) * 64]);
#pragma unroll
        for (int c = 0; c < 2; ++c)
            gload_lds16(Bg + (size_t)c * 8 * 1024 + k0,
                        &Bs[bf][(wave * 16 + c * 8) * 64]);
    };

    GSTAGE(0);
    for (int kt = 0; kt < 16; ++kt) {
        asm volatile("s_waitcnt vmcnt(0)" ::: "memory");  // buf[kt&1] published
        __builtin_amdgcn_s_barrier();
        if (kt < 15) GSTAGE(kt + 1);                      // DMA flies under MFMA
        const int bf = kt & 1;
#pragma unroll
        for (int ks = 0; ks < 2; ++ks) {
            bf16x8 av[4], bv[2];
#pragma unroll
            for (int i = 0; i < 4; ++i)
                av[i] = *(const bf16x8*)&As[bf][(wr * 64 + i * 16 + lo) * 64 + ks * 32 + hi * 8];
#pragma unroll
            for (int i = 0; i < 2; ++i)
                bv[i] = *(const bf16x8*)&Bs[bf][(wc * 32 + i * 16 + lo) * 64 + ks * 32 + hi * 8];
#pragma unroll
            for (int mi = 0; mi < 4; ++mi)
#pragma unroll
                for (int ni = 0; ni < 2; ++ni)
                    acc[mi][ni] = __builtin_amdgcn_mfma_f32_16x16x32_bf16(
                        av[mi], bv[ni], acc[mi][ni], 0, 0, 0);
        }
    }

#pragma unroll
    for (int mi = 0; mi < 4; ++mi) {
#pragma unroll
        for (int ni = 0; ni < 2; ++ni) {
            const int n = n_base + wc * 32 + ni * 16 + lo;
            if (IS_OUT) {
                const float bsv = bias[n];
#pragma unroll
                for (int i = 0; i < 4; ++i) {
                    const int m = m_base + wr * 64 + mi * 16 + hi * 4 + i;
                    outp[(size_t)m * 1024 + n] = acc[mi][ni][i] + bsv;
                }
            } else {
                const int h = n >> 6, d = n & 63;
                if (z == 2) {   // V transposed [B,H,dh,N], kv pi-permuted
                    const int m0 = m_base + wr * 64 + mi * 16 + hi * 4;
                    const int b = m0 >> 11, ns = m0 & 2047;
                    const int k6 = ns & 63;          // ns % 4 == 0 (hi*4)
                    const int nsp = (ns & ~63) | (k6 & 0x20) |
                                    ((k6 & 0x10) >> 2) | ((k6 & 0x0C) << 1);
                    s16x4 pk;
#pragma unroll
                    for (int i = 0; i < 4; ++i) pk[i] = f2bf(acc[mi][ni][i]);
                    *(s16x4*)&vtb[(((size_t)b * 16 + h) * 64 + d) * 2048 + nsp] = pk;
                } else {
                    short* dstp = (z == 0) ? qb : kb;
                    // Q scale folded with log2(e) so softmax uses exp2 directly
                    const float scl = (z == 0) ? 0.18033688011112042f : 1.0f;
#pragma unroll
                    for (int i = 0; i < 4; ++i) {
                        const int m = m_base + wr * 64 + mi * 16 + hi * 4 + i;
                        const int b = m >> 11, ns = m & 2047;
                        dstp[(((size_t)b * 16 + h) * 2048 + ns) * 64 + d] =
                            f2bf(acc[mi][ni][i] * scl);
                    }
                }
            }
        }
    }
}

// ---------------- flash attention: R18-verified (56.5us) -- verbatim --------
// grid 512 (16 q-tiles x 32 bh), 4 waves x 32 q-rows. KV tile 64.
// 3-buffer K/V ring, no P_lds (48KB), zero bank conflicts, single barrier
// per tile, 6-periodic unroll with compile-time buffer indices, 2
// lane-constant LDS vaddrs + literal offsets, precomputed staging pointers.
// NOTE: structural loop edits regress (R9/R10/R12 maxless, R19 asym ring:
// VGPR inflation -> occupancy collapse). R18 is the attn plateau.

#define QKT16B_(BUFN, S) do {                                                  \
    const char* kb_ = (const char*)K_lds[BUFN];                                \
    bf16x8 kf_[4];                                                             \
    _Pragma("unroll")                                                          \
    for (int mi = 0; mi < 4; ++mi)                                             \
        kf_[mi] = *(const bf16x8*)(kb_ + koff0 + mi * 2048);                   \
    _Pragma("unroll")                                                          \
    for (int mi = 0; mi < 4; ++mi)                                             \
        _Pragma("unroll")                                                      \
        for (int nf = 0; nf < 2; ++nf)                                         \
            S[mi][nf] = __builtin_amdgcn_mfma_f32_16x16x32_bf16(               \
                kf_[mi], qf[nf][0], Z4, 0, 0, 0);                              \
    _Pragma("unroll")                                                          \
    for (int mi = 0; mi < 4; ++mi)                                             \
        kf_[mi] = *(const bf16x8*)(kb_ + koff1 + mi * 2048);                   \
    _Pragma("unroll")                                                          \
    for (int mi = 0; mi < 4; ++mi)                                             \
        _Pragma("unroll")                                                      \
        for (int nf = 0; nf < 2; ++nf)                                         \
            S[mi][nf] = __builtin_amdgcn_mfma_f32_16x16x32_bf16(               \
                kf_[mi], qf[nf][1], S[mi][nf], 0, 0, 0);                       \
    } while (0)

#define STAGE_(T_, BUF_) do {                                                  \
    const size_t go_ = (size_t)(T_) * gstep;                                   \
    _Pragma("unroll")                                                          \
    for (int c = 0; c < 4; ++c) {                                              \
        void* dst_ = (stV == 0) ? (void*)&K_lds[BUF_][(rbase + c * 8) * 64]    \
                                : (void*)&V_lds[BUF_][(rbase + c * 8) * 64];   \
        gload_lds16(gp[c] + go_, dst_);                                        \
    } } while (0)

#define HALF16_(T, SC, SN, DOQ, BUFC, BUFN, BUFS, DOS) do {                    \
    asm volatile("s_waitcnt vmcnt(0)" ::: "memory");                           \
    __builtin_amdgcn_s_barrier();                                              \
    if (DOQ) {                                                                 \
        __builtin_amdgcn_s_setprio(1);                                         \
        QKT16B_(BUFN, SN);                                                     \
        __builtin_amdgcn_s_setprio(0);                                         \
    }                                                                          \
    if (DOS) STAGE_((T) + 2, BUFS);   /* DMA flies under softmax+PV */         \
    /* ---- softmax on SC: per-lane max fast path ---- */                      \
    float pm_[2];                                                              \
    _Pragma("unroll")                                                          \
    for (int nf = 0; nf < 2; ++nf) {                                           \
        float a0 = fmaxf(fmaxf(SC[0][nf][0], SC[0][nf][1]),                    \
                         fmaxf(SC[0][nf][2], SC[0][nf][3]));                   \
        float a1 = fmaxf(fmaxf(SC[1][nf][0], SC[1][nf][1]),                    \
                         fmaxf(SC[1][nf][2], SC[1][nf][3]));                   \
        float a2 = fmaxf(fmaxf(SC[2][nf][0], SC[2][nf][1]),                    \
                         fmaxf(SC[2][nf][2], SC[2][nf][3]));                   \
        float a3 = fmaxf(fmaxf(SC[3][nf][0], SC[3][nf][1]),                    \
                         fmaxf(SC[3][nf][2], SC[3][nf][3]));                   \
        pm_[nf] = fmaxf(fmaxf(a0, a1), fmaxf(a2, a3));                         \
    }                                                                          \
    const int keep_ = (pm_[0] <= mrow[0] + 8.f) && (pm_[1] <= mrow[1] + 8.f);  \
    if (!__all(keep_)) {      /* rare: full row reduce + rescale */            \
        float alpha_[2];                                                       \
        _Pragma("unroll")                                                      \
        for (int nf = 0; nf < 2; ++nf) {                                       \
            float m4 = pm_[nf];                                                \
            m4 = fmaxf(m4, __shfl_xor(m4, 16));                                \
            m4 = fmaxf(m4, __shfl_xor(m4, 32));                                \
            const float mn = fmaxf(mrow[nf], m4);                              \
            alpha_[nf] = __builtin_amdgcn_exp2f(mrow[nf] - mn);                \
            mrow[nf]  = mn;                                                    \
            lrow[nf] *= alpha_[nf];                                            \
        }                                                                      \
        _Pragma("unroll")                                                      \
        for (int mi = 0; mi < 2; ++mi)                                         \
            _Pragma("unroll")                                                  \
            for (int i = 0; i < 4; ++i) {                                      \
                const float av = __shfl(alpha_[mi], hi * 4 + i);               \
                _Pragma("unroll")                                              \
                for (int nf = 0; nf < 4; ++nf) oacc[mi][nf][i] *= av;          \
            }                                                                  \
    }                                                                          \
    _Pragma("unroll")                                                          \
    for (int nf = 0; nf < 2; ++nf) {     /* per-lane partial sum, no shfl */   \
        float s0 = 0.f, s1 = 0.f, s2 = 0.f, s3 = 0.f;                          \
        _Pragma("unroll")                                                      \
        for (int mi = 0; mi < 4; ++mi) {                                       \
            SC[mi][nf][0] = __builtin_amdgcn_exp2f(SC[mi][nf][0] - mrow[nf]);  \
            s0 += SC[mi][nf][0];                                               \
            SC[mi][nf][1] = __builtin_amdgcn_exp2f(SC[mi][nf][1] - mrow[nf]);  \
            s1 += SC[mi][nf][1];                                               \
            SC[mi][nf][2] = __builtin_amdgcn_exp2f(SC[mi][nf][2] - mrow[nf]);  \
            s2 += SC[mi][nf][2];                                               \
            SC[mi][nf][3] = __builtin_amdgcn_exp2f(SC[mi][nf][3] - mrow[nf]);  \
            s3 += SC[mi][nf][3];                                               \
        }                                                                      \
        lrow[nf] += (s0 + s1) + (s2 + s3);                                     \
    }                                                                          \
    /* ---- pack P to bf16 word pairs (own registers only) ---- */             \
    uint32_t W2_[4][2][2];                                                     \
    _Pragma("unroll")                                                          \
    for (int mi = 0; mi < 4; ++mi)                                             \
        _Pragma("unroll")                                                      \
        for (int nf = 0; nf < 2; ++nf) {                                       \
            W2_[mi][nf][0] = cvtpk_bf16(SC[mi][nf][0], SC[mi][nf][1]);         \
            W2_[mi][nf][1] = cvtpk_bf16(SC[mi][nf][2], SC[mi][nf][3]);         \
        }                                                                      \
    /* ---- O += P V: own-reg A-frags + pi-permuted V b128 reads ---- */       \
    __builtin_amdgcn_s_setprio(1);                                             \
    _Pragma("unroll")                                                          \
    for (int ks = 0; ks < 2; ++ks) {                                           \
        const char* vb_ = (const char*)V_lds[BUFC];                            \
        bf16x8 vf_[4];                                                         \
        _Pragma("unroll")                                                      \
        for (int nf = 0; nf < 4; ++nf)                                         \
            vf_[nf] = *(const bf16x8*)(vb_ + (ks ? koff1 : koff0) + nf * 2048);\
        _Pragma("unroll")                                                      \
        for (int mo = 0; mo < 2; ++mo) {                                       \
            union { uint32_t u[4]; bf16x8 v; } pk_;                            \
            pk_.u[0] = W2_[ks * 2][mo][0];     pk_.u[1] = W2_[ks * 2][mo][1];  \
            pk_.u[2] = W2_[ks * 2 + 1][mo][0]; pk_.u[3] = W2_[ks * 2 + 1][mo][1]; \
            _Pragma("unroll")                                                  \
            for (int nf = 0; nf < 4; ++nf)                                     \
                oacc[mo][nf] = __builtin_amdgcn_mfma_f32_16x16x32_bf16(        \
                    pk_.v, vf_[nf], oacc[mo][nf], 0, 0, 0);                    \
        }                                                                      \
    }                                                                          \
    __builtin_amdgcn_s_setprio(0);                                             \
    } while (0)

__global__ __launch_bounds__(256) void attn(
    const short* __restrict__ qg, const short* __restrict__ kg,
    const short* __restrict__ vtg, short* __restrict__ ob)
{
    __shared__ short K_lds[3][64 * 64];
    __shared__ short V_lds[3][64 * 64];

    const int tid  = threadIdx.x;
    const int wave = tid >> 6, lane = tid & 63;
    const int lo = lane & 15, hi = lane >> 4;
    // lane-constant LDS read addresses (whole kernel): granule swizzle
    const int koff0 = lo * 128 + ((hi ^ (lo & 7)) << 4);
    const int koff1 = koff0 ^ 64;

    int bid = blockIdx.y * 16 + blockIdx.x;       // 0..511
    bid = (bid & 7) * 64 + (bid >> 3);            // XCD swizzle (bijective)
    const int bh = bid >> 4;
    const int qw = (bid & 15) * 128 + wave * 32;

    // Q fragments in registers for the whole kernel (already * SCALE*log2e)
    bf16x8 qf[2][2];
#pragma unroll
    for (int nf = 0; nf < 2; ++nf)
#pragma unroll
        for (int ks = 0; ks < 2; ++ks)
            qf[nf][ks] = *(const bf16x8*)&qg[((size_t)bh * 2048 + qw + nf * 16 + lo) * 64 +
                                             ks * 32 + hi * 8];
    asm volatile("s_waitcnt vmcnt(0)" ::: "memory");   // keep vmcnt counting exact

    f32x4 oacc[2][4];
#pragma unroll
    for (int mi = 0; mi < 2; ++mi)
#pragma unroll
        for (int nf = 0; nf < 4; ++nf) oacc[mi][nf] = (f32x4){0.f, 0.f, 0.f, 0.f};
    float mrow[2] = {-1e30f, -1e30f};   // running max (log2 domain), q=nf*16+lo
    float lrow[2] = {0.f, 0.f};         // per-lane PARTIAL sums (reduced at end)
    const f32x4 Z4 = (f32x4){0.f, 0.f, 0.f, 0.f};  // zero C-operand

    const short* kgb = kg  + (size_t)bh * 2048 * 64;
    const short* vgb = vtg + (size_t)bh * 64 * 2048;

    const int stV = wave >> 1, rbase = (wave & 1) * 32;
    // precomputed per-lane staging pointers; per-tile offset = t * gstep
    const short* gp[4];
#pragma unroll
    for (int c = 0; c < 4; ++c) {
        const int r  = rbase + c * 8 + (lane >> 3);
        const int sg = (lane & 7) ^ (r & 7);         // inverse-swizzled src slot
        gp[c] = (stV == 0) ? (kgb + (size_t)r * 64 + sg * 8)
                           : (vgb + (size_t)r * 2048 + sg * 8);
    }
    const int gstep = (stV == 0) ? 4096 : 64;        // shorts per tile step

    STAGE_(0, 0); STAGE_(1, 1);

    f32x4 sA[4][2], sB[4][2];

    asm volatile("s_waitcnt vmcnt(4)" ::: "memory");   // STAGE(0) complete
    __builtin_amdgcn_s_barrier();
    QKT16B_(0, sA);

    for (int tb = 0; tb < 30; tb += 6) {
        HALF16_(tb + 0, sA, sB, 1, 0, 1, 2, 1);
        HALF16_(tb + 1, sB, sA, 1, 1, 2, 0, 1);
        HALF16_(tb + 2, sA, sB, 1, 2, 0, 1, 1);
        HALF16_(tb + 3, sB, sA, 1, 0, 1, 2, 1);
        HALF16_(tb + 4, sA, sB, 1, 1, 2, 0, 1);
        HALF16_(tb + 5, sB, sA, 1, 2, 0, 1, 1);
    }
    HALF16_(30, sA, sB, 1, 0, 1, 2, 0);
    HALF16_(31, sB, sA, 0, 1, 2, 0, 0);

    // -------- epilogue: reduce l across hi-groups, o /= l, write bf16 --------
    float lfull[2];
#pragma unroll
    for (int nf = 0; nf < 2; ++nf) {
        float ts = lrow[nf];
        ts += __shfl_xor(ts, 16);
        ts += __shfl_xor(ts, 32);
        lfull[nf] = ts;
    }
    const int b = bh >> 4, h = bh & 15;
#pragma unroll
    for (int mi = 0; mi < 2; ++mi)
#pragma unroll
        for (int i = 0; i < 4; ++i) {
            const float lv = __shfl(lfull[mi], hi * 4 + i);
            const float r  = 1.0f / lv;
            const int qrow = qw + mi * 16 + hi * 4 + i;
#pragma unroll
            for (int nf = 0; nf < 4; ++nf)
                ob[((size_t)b * 2048 + qrow) * 1024 + h * 64 + nf * 16 + lo] =
                    f2bf(oacc[mi][nf][i] * r);
        }
}

// ---------------------------------------------------------------------------
extern "C" void kernel_launch(void* const* d_in, const int* in_sizes, int n_in,
                              void* d_out, int out_size, void* d_ws, size_t ws_size,
                              hipStream_t stream) {
    const float* x   = (const float*)d_in[0];
    const float* Wq  = (const float*)d_in[1];
    const float* Wk  = (const float*)d_in[2];
    const float* Wv  = (const float*)d_in[3];
    const float* Wo  = (const float*)d_in[4];
    const float* bo  = (const float*)d_in[5];
    float* outp = (float*)d_out;

    char* ws = (char*)d_ws;
    short* xb  = (short*)(ws);                     // 8 MB  (4096x1024 bf16)
    short* qb  = (short*)(ws + (8u  << 20));       // 8 MB  [B,H,N,dh]
    short* kb  = (short*)(ws + (16u << 20));       // 8 MB  [B,H,N,dh]
    short* vtb = (short*)(ws + (24u << 20));       // 8 MB  [B,H,dh,N] (kv pi-perm)
    short* ob  = (short*)(ws + (32u << 20));       // 8 MB  (4096x1024 bf16)
    short* wqb = (short*)(ws + (40u << 20));       // 2 MB each
    short* wkb = (short*)(ws + (42u << 20));
    short* wvb = (short*)(ws + (44u << 20));
    short* wob = (short*)(ws + (46u << 20));

    cvt_all<<<8192, 256, 0, stream>>>(x, Wq, Wk, Wv, Wo, xb, wqb, wkb, wvb, wob);
    gemm_bt<false><<<dim3(16, 32, 3), 256, 0, stream>>>(
        xb, wqb, wkb, wvb, qb, kb, vtb, nullptr, nullptr);
    attn<<<dim3(16, 32), 256, 0, stream>>>(qb, kb, vtb, ob);
    gemm_bt<true><<<dim3(16, 32, 1), 256, 0, stream>>>(
        ob, wob, nullptr, nullptr, nullptr, nullptr, nullptr, outp, bo);
}

// Round 22
// 117.029 us; speedup vs baseline: 1.0089x; 1.0089x over previous
//
#include <hip/hip_runtime.h>
#include <stdint.h>

// Problem constants: B=2, N=2048, D=1024, HEADS=16, DH=64, SCALE=0.125
using bf16x8 = __attribute__((ext_vector_type(8))) short;
using f32x4  = __attribute__((ext_vector_type(4))) float;
using s16x4  = __attribute__((ext_vector_type(4))) short;

__device__ __forceinline__ short f2bf(float f) {
    union { float f; uint32_t u; } v; v.f = f;
    uint32_t u = v.u;
    uint32_t r = (u + 0x7fffu + ((u >> 16) & 1u)) >> 16;  // RNE
    return (short)r;
}

__device__ __forceinline__ uint32_t cvtpk_bf16(float a, float b) {
    uint32_t r;
    asm("v_cvt_pk_bf16_f32 %0, %1, %2" : "=v"(r) : "v"(a), "v"(b));
    return r;  // lo = bf16(a), hi = bf16(b)
}

// async global->LDS, 16B per lane; LDS dest = wave-uniform base + lane*16
__device__ __forceinline__ void gload_lds16(const void* g, void* l) {
    __builtin_amdgcn_global_load_lds(
        reinterpret_cast<const uint32_t __attribute__((address_space(1)))*>(
            reinterpret_cast<uintptr_t>(g)),
        reinterpret_cast<uint32_t __attribute__((address_space(3)))*>(
            reinterpret_cast<uintptr_t>(l)),
        16, 0, 0);
}

// ---------------- fused fp32 -> bf16 conversion (x + 4 weights) -------------
__global__ __launch_bounds__(256) void cvt_all(
    const float* __restrict__ x, const float* __restrict__ wq,
    const float* __restrict__ wk, const float* __restrict__ wv,
    const float* __restrict__ wo,
    short* __restrict__ xb, short* __restrict__ wqb, short* __restrict__ wkb,
    short* __restrict__ wvb, short* __restrict__ wob)
{
    int i = blockIdx.x * 256 + threadIdx.x;   // float4 index, total 2097152
    const float* src; short* dst; int off;
    if      (i < 1048576) { src = x;  dst = xb;  off = i; }
    else if (i < 1310720) { src = wq; dst = wqb; off = i - 1048576; }
    else if (i < 1572864) { src = wk; dst = wkb; off = i - 1310720; }
    else if (i < 1835008) { src = wv; dst = wvb; off = i - 1572864; }
    else                  { src = wo; dst = wob; off = i - 1835008; }
    float4 f = ((const float4*)src)[off];
    s16x4 r; r[0] = f2bf(f.x); r[1] = f2bf(f.y); r[2] = f2bf(f.z); r[3] = f2bf(f.w);
    ((s16x4*)dst)[off] = r;
}

// ---------------- GEMM: C = A(MxK) * B(NxK)^T, bf16, 128x64 tile ------------
// Grid 1536 (QKV) / 512 (out), 48KB LDS, 3 blocks/CU. XCD-bijective swizzle.
// 2-buffer LDS ring, counted vmcnt(6) (R20-verified best; R21's single-
// barrier variant was neutral/-1us -> reverted).
// V^T output (z==2) is written KV-PI-PERMUTED (R16-verified).
template <bool IS_OUT>
__global__ __launch_bounds__(256) void gemm_bt(
    const short* __restrict__ A,
    const short* __restrict__ Bq, const short* __restrict__ Bk,
    const short* __restrict__ Bv,
    short* __restrict__ qb, short* __restrict__ kb, short* __restrict__ vtb,
    float* __restrict__ outp, const float* __restrict__ bias)
{
    __shared__ short As[2][128 * 64];
    __shared__ short Bs[2][64 * 64];
    const int tid  = threadIdx.x;
    const int wave = tid >> 6, lane = tid & 63;
    const int lo = lane & 15, hi = lane >> 4;

    // swizzle: linear id -> XCD-contiguous chunk, then decomposition
    const int nwg = gridDim.x * gridDim.y * gridDim.z;
    int lin = blockIdx.x + blockIdx.y * gridDim.x +
              blockIdx.z * gridDim.x * gridDim.y;
    const int s = (lin & 7) * (nwg >> 3) + (lin >> 3);
    const int m_base = ((s >> 4) & 31) * 128;
    const int n_base = (s & 15) * 64;
    const int z = IS_OUT ? 0 : (s >> 9);

    const short* Bw = IS_OUT ? Bq : (z == 0 ? Bq : (z == 1 ? Bk : Bv));
    const int wr = wave >> 1, wc = wave & 1;

    f32x4 acc[4][2];
#pragma unroll
    for (int i = 0; i < 4; ++i)
#pragma unroll
        for (int j = 0; j < 2; ++j) acc[i][j] = (f32x4){0.f, 0.f, 0.f, 0.f};

    const int se = (lane & 7) * 8;
    const short* Ag = A  + (size_t)(m_base + wave * 32 + (lane >> 3)) * 1024 + se;
    const short* Bg = Bw + (size_t)(n_base + wave * 16 + (lane >> 3)) * 1024 + se;

    auto GSTAGE = [&](int kt) {
        const int k0 = kt * 64, bf = kt & 1;
#pragma unroll
        for (int c = 0; c < 4; ++c)
            gload_lds16(Ag + (size_t)c * 8 * 1024 + k0, &As[bf][(wave * 32 + c * 8) * 64]);
#pragma unroll
        for (int c = 0; c < 2; ++c)
            gload_lds16(Bg + (size_t)c * 8 * 1024 + k0,
                        &Bs[bf][(wave * 16 + c * 8) * 64]);
    };

    GSTAGE(0);
    for (int kt = 0; kt < 16; ++kt) {
        if (kt < 15) {
            GSTAGE(kt + 1);                                  // next tile in flight
            asm volatile("s_waitcnt vmcnt(6)" ::: "memory"); // tile kt's 6 done
        } else {
            asm volatile("s_waitcnt vmcnt(0)" ::: "memory");
        }
        __builtin_amdgcn_s_barrier();
        const int bf = kt & 1;
#pragma unroll
        for (int ks = 0; ks < 2; ++ks) {
            bf16x8 av[4], bv[2];
#pragma unroll
            for (int i = 0; i < 4; ++i)
                av[i] = *(const bf16x8*)&As[bf][(wr * 64 + i * 16 + lo) * 64 + ks * 32 + hi * 8];
#pragma unroll
            for (int i = 0; i < 2; ++i)
                bv[i] = *(const bf16x8*)&Bs[bf][(wc * 32 + i * 16 + lo) * 64 + ks * 32 + hi * 8];
#pragma unroll
            for (int mi = 0; mi < 4; ++mi)
#pragma unroll
                for (int ni = 0; ni < 2; ++ni)
                    acc[mi][ni] = __builtin_amdgcn_mfma_f32_16x16x32_bf16(
                        av[mi], bv[ni], acc[mi][ni], 0, 0, 0);
        }
        asm volatile("s_waitcnt lgkmcnt(0)" ::: "memory");   // reads done before
        __builtin_amdgcn_s_barrier();                        // next GSTAGE overwrite
    }

#pragma unroll
    for (int mi = 0; mi < 4; ++mi) {
#pragma unroll
        for (int ni = 0; ni < 2; ++ni) {
            const int n = n_base + wc * 32 + ni * 16 + lo;
            if (IS_OUT) {
                const float bsv = bias[n];
#pragma unroll
                for (int i = 0; i < 4; ++i) {
                    const int m = m_base + wr * 64 + mi * 16 + hi * 4 + i;
                    outp[(size_t)m * 1024 + n] = acc[mi][ni][i] + bsv;
                }
            } else {
                const int h = n >> 6, d = n & 63;
                if (z == 2) {   // V transposed [B,H,dh,N], kv pi-permuted
                    const int m0 = m_base + wr * 64 + mi * 16 + hi * 4;
                    const int b = m0 >> 11, ns = m0 & 2047;
                    const int k6 = ns & 63;          // ns % 4 == 0 (hi*4)
                    const int nsp = (ns & ~63) | (k6 & 0x20) |
                                    ((k6 & 0x10) >> 2) | ((k6 & 0x0C) << 1);
                    s16x4 pk;
#pragma unroll
                    for (int i = 0; i < 4; ++i) pk[i] = f2bf(acc[mi][ni][i]);
                    *(s16x4*)&vtb[(((size_t)b * 16 + h) * 64 + d) * 2048 + nsp] = pk;
                } else {
                    short* dstp = (z == 0) ? qb : kb;
                    // Q scale folded with log2(e) so softmax uses exp2 directly
                    const float scl = (z == 0) ? 0.18033688011112042f : 1.0f;
#pragma unroll
                    for (int i = 0; i < 4; ++i) {
                        const int m = m_base + wr * 64 + mi * 16 + hi * 4 + i;
                        const int b = m >> 11, ns = m & 2047;
                        dstp[(((size_t)b * 16 + h) * 2048 + ns) * 64 + d] =
                            f2bf(acc[mi][ni][i] * scl);
                    }
                }
            }
        }
    }
}

// ---------------- flash attention: R18-verified (56.5us) -- verbatim --------
// grid 512 (16 q-tiles x 32 bh), 4 waves x 32 q-rows. KV tile 64.
// 3-buffer K/V ring, no P_lds (48KB), zero bank conflicts, single barrier
// per tile, 6-periodic unroll with compile-time buffer indices, 2
// lane-constant LDS vaddrs + literal offsets, precomputed staging pointers.
// NOTE: structural loop edits regress (R9/R10/R12 maxless, R19 asym ring:
// VGPR inflation -> occupancy collapse). R18 is the attn plateau.

#define QKT16B_(BUFN, S) do {                                                  \
    const char* kb_ = (const char*)K_lds[BUFN];                                \
    bf16x8 kf_[4];                                                             \
    _Pragma("unroll")                                                          \
    for (int mi = 0; mi < 4; ++mi)                                             \
        kf_[mi] = *(const bf16x8*)(kb_ + koff0 + mi * 2048);                   \
    _Pragma("unroll")                                                          \
    for (int mi = 0; mi < 4; ++mi)                                             \
        _Pragma("unroll")                                                      \
        for (int nf = 0; nf < 2; ++nf)                                         \
            S[mi][nf] = __builtin_amdgcn_mfma_f32_16x16x32_bf16(               \
                kf_[mi], qf[nf][0], Z4, 0, 0, 0);                              \
    _Pragma("unroll")                                                          \
    for (int mi = 0; mi < 4; ++mi)                                             \
        kf_[mi] = *(const bf16x8*)(kb_ + koff1 + mi * 2048);                   \
    _Pragma("unroll")                                                          \
    for (int mi = 0; mi < 4; ++mi)                                             \
        _Pragma("unroll")                                                      \
        for (int nf = 0; nf < 2; ++nf)                                         \
            S[mi][nf] = __builtin_amdgcn_mfma_f32_16x16x32_bf16(               \
                kf_[mi], qf[nf][1], S[mi][nf], 0, 0, 0);                       \
    } while (0)

#define STAGE_(T_, BUF_) do {                                                  \
    const size_t go_ = (size_t)(T_) * gstep;                                   \
    _Pragma("unroll")                                                          \
    for (int c = 0; c < 4; ++c) {                                              \
        void* dst_ = (stV == 0) ? (void*)&K_lds[BUF_][(rbase + c * 8) * 64]    \
                                : (void*)&V_lds[BUF_][(rbase + c * 8) * 64];   \
        gload_lds16(gp[c] + go_, dst_);                                        \
    } } while (0)

#define HALF16_(T, SC, SN, DOQ, BUFC, BUFN, BUFS, DOS) do {                    \
    asm volatile("s_waitcnt vmcnt(0)" ::: "memory");                           \
    __builtin_amdgcn_s_barrier();                                              \
    if (DOQ) {                                                                 \
        __builtin_amdgcn_s_setprio(1);                                         \
        QKT16B_(BUFN, SN);                                                     \
        __builtin_amdgcn_s_setprio(0);                                         \
    }                                                                          \
    if (DOS) STAGE_((T) + 2, BUFS);   /* DMA flies under softmax+PV */         \
    /* ---- softmax on SC: per-lane max fast path ---- */                      \
    float pm_[2];                                                              \
    _Pragma("unroll")                                                          \
    for (int nf = 0; nf < 2; ++nf) {                                           \
        float a0 = fmaxf(fmaxf(SC[0][nf][0], SC[0][nf][1]),                    \
                         fmaxf(SC[0][nf][2], SC[0][nf][3]));                   \
        float a1 = fmaxf(fmaxf(SC[1][nf][0], SC[1][nf][1]),                    \
                         fmaxf(SC[1][nf][2], SC[1][nf][3]));                   \
        float a2 = fmaxf(fmaxf(SC[2][nf][0], SC[2][nf][1]),                    \
                         fmaxf(SC[2][nf][2], SC[2][nf][3]));                   \
        float a3 = fmaxf(fmaxf(SC[3][nf][0], SC[3][nf][1]),                    \
                         fmaxf(SC[3][nf][2], SC[3][nf][3]));                   \
        pm_[nf] = fmaxf(fmaxf(a0, a1), fmaxf(a2, a3));                         \
    }                                                                          \
    const int keep_ = (pm_[0] <= mrow[0] + 8.f) && (pm_[1] <= mrow[1] + 8.f);  \
    if (!__all(keep_)) {      /* rare: full row reduce + rescale */            \
        float alpha_[2];                                                       \
        _Pragma("unroll")                                                      \
        for (int nf = 0; nf < 2; ++nf) {                                       \
            float m4 = pm_[nf];                                                \
            m4 = fmaxf(m4, __shfl_xor(m4, 16));                                \
            m4 = fmaxf(m4, __shfl_xor(m4, 32));                                \
            const float mn = fmaxf(mrow[nf], m4);                              \
            alpha_[nf] = __builtin_amdgcn_exp2f(mrow[nf] - mn);                \
            mrow[nf]  = mn;                                                    \
            lrow[nf] *= alpha_[nf];                                            \
        }                                                                      \
        _Pragma("unroll")                                                      \
        for (int mi = 0; mi < 2; ++mi)                                         \
            _Pragma("unroll")                                                  \
            for (int i = 0; i < 4; ++i) {                                      \
                const float av = __shfl(alpha_[mi], hi * 4 + i);               \
                _Pragma("unroll")                                              \
                for (int nf = 0; nf < 4; ++nf) oacc[mi][nf][i] *= av;          \
            }                                                                  \
    }                                                                          \
    _Pragma("unroll")                                                          \
    for (int nf = 0; nf < 2; ++nf) {     /* per-lane partial sum, no shfl */   \
        float s0 = 0.f, s1 = 0.f, s2 = 0.f, s3 = 0.f;                          \
        _Pragma("unroll")                                                      \
        for (int mi = 0; mi < 4; ++mi) {                                       \
            SC[mi][nf][0] = __builtin_amdgcn_exp2f(SC[mi][nf][0] - mrow[nf]);  \
            s0 += SC[mi][nf][0];                                               \
            SC[mi][nf][1] = __builtin_amdgcn_exp2f(SC[mi][nf][1] - mrow[nf]);  \
            s1 += SC[mi][nf][1];                                               \
            SC[mi][nf][2] = __builtin_amdgcn_exp2f(SC[mi][nf][2] - mrow[nf]);  \
            s2 += SC[mi][nf][2];                                               \
            SC[mi][nf][3] = __builtin_amdgcn_exp2f(SC[mi][nf][3] - mrow[nf]);  \
            s3 += SC[mi][nf][3];                                               \
        }                                                                      \
        lrow[nf] += (s0 + s1) + (s2 + s3);                                     \
    }                                                                          \
    /* ---- pack P to bf16 word pairs (own registers only) ---- */             \
    uint32_t W2_[4][2][2];                                                     \
    _Pragma("unroll")                                                          \
    for (int mi = 0; mi < 4; ++mi)                                             \
        _Pragma("unroll")                                                      \
        for (int nf = 0; nf < 2; ++nf) {                                       \
            W2_[mi][nf][0] = cvtpk_bf16(SC[mi][nf][0], SC[mi][nf][1]);         \
            W2_[mi][nf][1] = cvtpk_bf16(SC[mi][nf][2], SC[mi][nf][3]);         \
        }                                                                      \
    /* ---- O += P V: own-reg A-frags + pi-permuted V b128 reads ---- */       \
    __builtin_amdgcn_s_setprio(1);                                             \
    _Pragma("unroll")                                                          \
    for (int ks = 0; ks < 2; ++ks) {                                           \
        const char* vb_ = (const char*)V_lds[BUFC];                            \
        bf16x8 vf_[4];                                                         \
        _Pragma("unroll")                                                      \
        for (int nf = 0; nf < 4; ++nf)                                         \
            vf_[nf] = *(const bf16x8*)(vb_ + (ks ? koff1 : koff0) + nf * 2048);\
        _Pragma("unroll")                                                      \
        for (int mo = 0; mo < 2; ++mo) {                                       \
            union { uint32_t u[4]; bf16x8 v; } pk_;                            \
            pk_.u[0] = W2_[ks * 2][mo][0];     pk_.u[1] = W2_[ks * 2][mo][1];  \
            pk_.u[2] = W2_[ks * 2 + 1][mo][0]; pk_.u[3] = W2_[ks * 2 + 1][mo][1]; \
            _Pragma("unroll")                                                  \
            for (int nf = 0; nf < 4; ++nf)                                     \
                oacc[mo][nf] = __builtin_amdgcn_mfma_f32_16x16x32_bf16(        \
                    pk_.v, vf_[nf], oacc[mo][nf], 0, 0, 0);                    \
        }                                                                      \
    }                                                                          \
    __builtin_amdgcn_s_setprio(0);                                             \
    } while (0)

__global__ __launch_bounds__(256) void attn(
    const short* __restrict__ qg, const short* __restrict__ kg,
    const short* __restrict__ vtg, short* __restrict__ ob)
{
    __shared__ short K_lds[3][64 * 64];
    __shared__ short V_lds[3][64 * 64];

    const int tid  = threadIdx.x;
    const int wave = tid >> 6, lane = tid & 63;
    const int lo = lane & 15, hi = lane >> 4;
    // lane-constant LDS read addresses (whole kernel): granule swizzle
    const int koff0 = lo * 128 + ((hi ^ (lo & 7)) << 4);
    const int koff1 = koff0 ^ 64;

    int bid = blockIdx.y * 16 + blockIdx.x;       // 0..511
    bid = (bid & 7) * 64 + (bid >> 3);            // XCD swizzle (bijective)
    const int bh = bid >> 4;
    const int qw = (bid & 15) * 128 + wave * 32;

    // Q fragments in registers for the whole kernel (already * SCALE*log2e)
    bf16x8 qf[2][2];
#pragma unroll
    for (int nf = 0; nf < 2; ++nf)
#pragma unroll
        for (int ks = 0; ks < 2; ++ks)
            qf[nf][ks] = *(const bf16x8*)&qg[((size_t)bh * 2048 + qw + nf * 16 + lo) * 64 +
                                             ks * 32 + hi * 8];
    asm volatile("s_waitcnt vmcnt(0)" ::: "memory");   // keep vmcnt counting exact

    f32x4 oacc[2][4];
#pragma unroll
    for (int mi = 0; mi < 2; ++mi)
#pragma unroll
        for (int nf = 0; nf < 4; ++nf) oacc[mi][nf] = (f32x4){0.f, 0.f, 0.f, 0.f};
    float mrow[2] = {-1e30f, -1e30f};   // running max (log2 domain), q=nf*16+lo
    float lrow[2] = {0.f, 0.f};         // per-lane PARTIAL sums (reduced at end)
    const f32x4 Z4 = (f32x4){0.f, 0.f, 0.f, 0.f};  // zero C-operand

    const short* kgb = kg  + (size_t)bh * 2048 * 64;
    const short* vgb = vtg + (size_t)bh * 64 * 2048;

    const int stV = wave >> 1, rbase = (wave & 1) * 32;
    // precomputed per-lane staging pointers; per-tile offset = t * gstep
    const short* gp[4];
#pragma unroll
    for (int c = 0; c < 4; ++c) {
        const int r  = rbase + c * 8 + (lane >> 3);
        const int sg = (lane & 7) ^ (r & 7);         // inverse-swizzled src slot
        gp[c] = (stV == 0) ? (kgb + (size_t)r * 64 + sg * 8)
                           : (vgb + (size_t)r * 2048 + sg * 8);
    }
    const int gstep = (stV == 0) ? 4096 : 64;        // shorts per tile step

    STAGE_(0, 0); STAGE_(1, 1);

    f32x4 sA[4][2], sB[4][2];

    asm volatile("s_waitcnt vmcnt(4)" ::: "memory");   // STAGE(0) complete
    __builtin_amdgcn_s_barrier();
    QKT16B_(0, sA);

    for (int tb = 0; tb < 30; tb += 6) {
        HALF16_(tb + 0, sA, sB, 1, 0, 1, 2, 1);
        HALF16_(tb + 1, sB, sA, 1, 1, 2, 0, 1);
        HALF16_(tb + 2, sA, sB, 1, 2, 0, 1, 1);
        HALF16_(tb + 3, sB, sA, 1, 0, 1, 2, 1);
        HALF16_(tb + 4, sA, sB, 1, 1, 2, 0, 1);
        HALF16_(tb + 5, sB, sA, 1, 2, 0, 1, 1);
    }
    HALF16_(30, sA, sB, 1, 0, 1, 2, 0);
    HALF16_(31, sB, sA, 0, 1, 2, 0, 0);

    // -------- epilogue: reduce l across hi-groups, o /= l, write bf16 --------
    float lfull[2];
#pragma unroll
    for (int nf = 0; nf < 2; ++nf) {
        float ts = lrow[nf];
        ts += __shfl_xor(ts, 16);
        ts += __shfl_xor(ts, 32);
        lfull[nf] = ts;
    }
    const int b = bh >> 4, h = bh & 15;
#pragma unroll
    for (int mi = 0; mi < 2; ++mi)
#pragma unroll
        for (int i = 0; i < 4; ++i) {
            const float lv = __shfl(lfull[mi], hi * 4 + i);
            const float r  = 1.0f / lv;
            const int qrow = qw + mi * 16 + hi * 4 + i;
#pragma unroll
            for (int nf = 0; nf < 4; ++nf)
                ob[((size_t)b * 2048 + qrow) * 1024 + h * 64 + nf * 16 + lo] =
                    f2bf(oacc[mi][nf][i] * r);
        }
}

// ---------------------------------------------------------------------------
extern "C" void kernel_launch(void* const* d_in, const int* in_sizes, int n_in,
                              void* d_out, int out_size, void* d_ws, size_t ws_size,
                              hipStream_t stream) {
    const float* x   = (const float*)d_in[0];
    const float* Wq  = (const float*)d_in[1];
    const float* Wk  = (const float*)d_in[2];
    const float* Wv  = (const float*)d_in[3];
    const float* Wo  = (const float*)d_in[4];
    const float* bo  = (const float*)d_in[5];
    float* outp = (float*)d_out;

    char* ws = (char*)d_ws;
    short* xb  = (short*)(ws);                     // 8 MB  (4096x1024 bf16)
    short* qb  = (short*)(ws + (8u  << 20));       // 8 MB  [B,H,N,dh]
    short* kb  = (short*)(ws + (16u << 20));       // 8 MB  [B,H,N,dh]
    short* vtb = (short*)(ws + (24u << 20));       // 8 MB  [B,H,dh,N] (kv pi-perm)
    short* ob  = (short*)(ws + (32u << 20));       // 8 MB  (4096x1024 bf16)
    short* wqb = (short*)(ws + (40u << 20));       // 2 MB each
    short* wkb = (short*)(ws + (42u << 20));
    short* wvb = (short*)(ws + (44u << 20));
    short* wob = (short*)(ws + (46u << 20));

    cvt_all<<<8192, 256, 0, stream>>>(x, Wq, Wk, Wv, Wo, xb, wqb, wkb, wvb, wob);
    gemm_bt<false><<<dim3(16, 32, 3), 256, 0, stream>>>(
        xb, wqb, wkb, wvb, qb, kb, vtb, nullptr, nullptr);
    attn<<<dim3(16, 32), 256, 0, stream>>>(qb, kb, vtb, ob);
    gemm_bt<true><<<dim3(16, 32, 1), 256, 0, stream>>>(
        ob, wob, nullptr, nullptr, nullptr, nullptr, nullptr, outp, bo);
}